// Round 18
// baseline (472.278 us; speedup 1.0000x reference)
//
#include <hip/hip_runtime.h>
#include <hip/hip_bf16.h>
#include <hip/hip_fp16.h>

// 5-layer GCN: out = relu( D^-1/2 (A+I) D^-1/2 (x W_l) + b_l ), x5.
// N=50000, E=800000, D=128.
//
// R18 = R16 (best, 414us) + weight folded into the producer:
//   gemm stores h' = dinv (.) (xW)  (fp32 mul in epilogue, free)
//   => out = di*(sum_e h'[src] + h'[self]) + b
//   => agg edges carry ONLY a ushort src index (ecol, 1.6MB):
//      - 8 indices load as one uint4 (vs 8 scalar edat loads)
//      - no fp16 weight unpack, no weight fma (plain adds)
//      - per-XCD resident set = 1.6MB h-slice + 1.6MB ecol < 4MB L2
//   R17's degree sort REVERTED (scattered offs/self/output accesses,
//   +10MB FETCH > divergence win).

#define GCN_DIM 128

typedef short bf16x8 __attribute__((ext_vector_type(8)));
typedef float f32x4 __attribute__((ext_vector_type(4)));

__device__ __forceinline__ unsigned short f2bf(float f) {
    unsigned int u = __float_as_uint(f);
    u += 0x7FFFu + ((u >> 16) & 1u);  // RTNE
    return (unsigned short)(u >> 16);
}
__device__ __forceinline__ float bf2f(unsigned short b) {
    return __uint_as_float(((unsigned int)b) << 16);
}
__device__ __forceinline__ float bflo(unsigned int p) { return __uint_as_float(p << 16); }
__device__ __forceinline__ float bfhi(unsigned int p) { return __uint_as_float(p & 0xFFFF0000u); }

// count + capture per-edge rank (old value of the atomic)
__global__ void count_kernel(const int* __restrict__ dst, int* __restrict__ cnt,
                             int* __restrict__ rank, int E) {
    int e = blockIdx.x * 256 + threadIdx.x;
    if (e < E) rank[e] = atomicAdd(&cnt[dst[e]], 1);
}

// ---- hierarchical scan (CSR offsets) ----
__global__ __launch_bounds__(256) void scan_part_kernel(const int* __restrict__ cnt,
                                                        int* __restrict__ loc,
                                                        int* __restrict__ bsum, int n) {
    __shared__ int s[256];
    int t = threadIdx.x;
    int i0 = blockIdx.x * 1024 + t * 4;
    int v0 = (i0 + 0 < n) ? cnt[i0 + 0] : 0;
    int v1 = (i0 + 1 < n) ? cnt[i0 + 1] : 0;
    int v2 = (i0 + 2 < n) ? cnt[i0 + 2] : 0;
    int v3 = (i0 + 3 < n) ? cnt[i0 + 3] : 0;
    int tsum = v0 + v1 + v2 + v3;
    s[t] = tsum;
    __syncthreads();
    for (int d = 1; d < 256; d <<= 1) {
        int u = (t >= d) ? s[t - d] : 0;
        __syncthreads();
        s[t] += u;
        __syncthreads();
    }
    int base = s[t] - tsum;
    if (i0 + 0 < n) loc[i0 + 0] = base; base += v0;
    if (i0 + 1 < n) loc[i0 + 1] = base; base += v1;
    if (i0 + 2 < n) loc[i0 + 2] = base; base += v2;
    if (i0 + 3 < n) loc[i0 + 3] = base;
    if (t == 255) bsum[blockIdx.x] = s[255];
}

__global__ __launch_bounds__(256) void scan_top_kernel(int* __restrict__ bsum, int nb) {
    __shared__ int s[256];
    int t = threadIdx.x;
    int v = (t < nb) ? bsum[t] : 0;
    s[t] = v;
    __syncthreads();
    for (int d = 1; d < 256; d <<= 1) {
        int u = (t >= d) ? s[t - d] : 0;
        __syncthreads();
        s[t] += u;
        __syncthreads();
    }
    if (t < nb) bsum[t] = s[t] - v;
}

// scan finalize + dinv (folded)
__global__ void scan_add_kernel(int* __restrict__ offs,
                                const int* __restrict__ bsum, const int* __restrict__ cnt,
                                float* __restrict__ dinv, int n, int E) {
    int i = blockIdx.x * 256 + threadIdx.x;
    if (i < n) {
        offs[i] = offs[i] + bsum[i >> 10];
        dinv[i] = rsqrtf((float)cnt[i] + 1.0f);
    }
    if (i == 0) offs[n] = E;
}

// CSR fill, atomic-free: ecol[offs[dst]+rank[e]] = (ushort)src.
__global__ void fill_kernel(const int* __restrict__ src, const int* __restrict__ dst,
                            const int* __restrict__ rank, const int* __restrict__ offs,
                            unsigned short* __restrict__ ecol, int E) {
    int e = blockIdx.x * 256 + threadIdx.x;
    if (e < E) {
        int d = dst[e];
        int s = src[e];
        int p = offs[d] + rank[e];
        ecol[p] = (unsigned short)s;
    }
}

// x0 fp32 -> (xh, xl) bf16 pair.
__global__ void split_x_kernel(const float* __restrict__ x, unsigned short* __restrict__ xh,
                               unsigned short* __restrict__ xl, int total) {
    int i = (blockIdx.x * 256 + threadIdx.x) * 4;
    if (i >= total) return;
    float4 v = *(const float4*)&x[i];
    ushort4 h4, l4;
    h4.x = f2bf(v.x); l4.x = f2bf(v.x - bf2f(h4.x));
    h4.y = f2bf(v.y); l4.y = f2bf(v.y - bf2f(h4.y));
    h4.z = f2bf(v.z); l4.z = f2bf(v.z - bf2f(h4.z));
    h4.w = f2bf(v.w); l4.w = f2bf(v.w - bf2f(h4.w));
    *(ushort4*)&xh[i] = h4;
    *(ushort4*)&xl[i] = l4;
}

// W [l][k][n] fp32 -> Wfh/Wfl in MFMA fragment order (A operand).
__global__ void wsplit_kernel(const float* __restrict__ Wall, unsigned short* __restrict__ Wfh,
                              unsigned short* __restrict__ Wfl, int total) {
    int idx = blockIdx.x * 256 + threadIdx.x;
    if (idx >= total) return;
    int l = idx >> 14;
    int rem = idx & 16383;
    int k = rem >> 7;
    int nn = rem & 127;
    float v = Wall[idx];
    unsigned short hi = f2bf(v);
    unsigned short lo = f2bf(v - bf2f(hi));
    int t = nn >> 4, ln = nn & 15;
    int ks = k >> 5, q = (k >> 3) & 3, j = k & 7;
    int o = ((((l << 5) | (t << 2) | ks) << 6) | (q << 4) | ln) * 8 + j;
    Wfh[o] = hi;
    Wfl[o] = lo;
}

// MFMA GEMM: h' = dinv (.) ((xh+xl) @ (Wh+Wl)), bf16 SLICE-MAJOR store
// h[(t*N + node)*16 + q*4]. 64 rows/block, 4 waves x 1 m-tile, t-pairs.
__global__ __launch_bounds__(256) void gemm_mfma_kernel(
    const unsigned short* __restrict__ xh, const unsigned short* __restrict__ xl,
    const unsigned short* __restrict__ Wfh, const unsigned short* __restrict__ Wfl,
    const float* __restrict__ dinv,
    unsigned short* __restrict__ h, int n) {
    __shared__ unsigned short ldsW[2][8192];  // 16KB hi + 16KB lo
    int tid = threadIdx.x;
    int wave = tid >> 6, lane = tid & 63;
    int q = lane >> 4, ln = lane & 15;
    int rowbase = blockIdx.x * 64 + wave * 16;
    int node = rowbase + ln;
    int arn = (node >= n) ? n - 1 : node;
    bf16x8 A[4][2];  // x fragments (B operand): [ks][hi/lo]
    {
        size_t base = (size_t)arn * GCN_DIM;
#pragma unroll
        for (int ks = 0; ks < 4; ks++) {
            A[ks][0] = *(const bf16x8*)&xh[base + ks * 32 + q * 8];
            A[ks][1] = *(const bf16x8*)&xl[base + ks * 32 + q * 8];
        }
    }
    float di = dinv[arn];
#pragma unroll
    for (int half = 0; half < 2; half++) {
        if (half) __syncthreads();  // wait for previous half's compute
        {
            const uint4* gh = (const uint4*)(Wfh + half * 8192);
            const uint4* gl = (const uint4*)(Wfl + half * 8192);
            uint4* sh = (uint4*)ldsW[0];
            uint4* sl = (uint4*)ldsW[1];
#pragma unroll
            for (int r = 0; r < 4; r++) {
                sh[tid + 256 * r] = gh[tid + 256 * r];
                sl[tid + 256 * r] = gl[tid + 256 * r];
            }
        }
        __syncthreads();
#pragma unroll
        for (int tp = 0; tp < 2; tp++) {  // t-pair
            int tta = tp * 2, ttb = tp * 2 + 1;
            f32x4 accA = (f32x4)(0.f), accB = (f32x4)(0.f);
#pragma unroll
            for (int ks = 0; ks < 4; ks++) {
                int foA = ((tta * 4 + ks) * 64 + lane) * 8;
                int foB = ((ttb * 4 + ks) * 64 + lane) * 8;
                bf16x8 bhA = *(const bf16x8*)&ldsW[0][foA];
                bf16x8 blA = *(const bf16x8*)&ldsW[1][foA];
                bf16x8 bhB = *(const bf16x8*)&ldsW[0][foB];
                bf16x8 blB = *(const bf16x8*)&ldsW[1][foB];
                accA = __builtin_amdgcn_mfma_f32_16x16x32_bf16(bhA, A[ks][0], accA, 0, 0, 0);
                accB = __builtin_amdgcn_mfma_f32_16x16x32_bf16(bhB, A[ks][0], accB, 0, 0, 0);
                accA = __builtin_amdgcn_mfma_f32_16x16x32_bf16(bhA, A[ks][1], accA, 0, 0, 0);
                accB = __builtin_amdgcn_mfma_f32_16x16x32_bf16(bhB, A[ks][1], accB, 0, 0, 0);
                accA = __builtin_amdgcn_mfma_f32_16x16x32_bf16(blA, A[ks][0], accA, 0, 0, 0);
                accB = __builtin_amdgcn_mfma_f32_16x16x32_bf16(blB, A[ks][0], accB, 0, 0, 0);
            }
            if (node < n) {
                int ta = half * 4 + tta, tb = half * 4 + ttb;
                ushort4 oA, oB;
                oA.x = f2bf(accA[0] * di); oA.y = f2bf(accA[1] * di);
                oA.z = f2bf(accA[2] * di); oA.w = f2bf(accA[3] * di);
                oB.x = f2bf(accB[0] * di); oB.y = f2bf(accB[1] * di);
                oB.z = f2bf(accB[2] * di); oB.w = f2bf(accB[3] * di);
                *(ushort4*)&h[((size_t)ta * n + node) * 16 + q * 4] = oA;
                *(ushort4*)&h[((size_t)tb * n + node) * 16 + q * 4] = oB;
            }
        }
    }
}

// Sliced aggregation on pre-scaled h': 8 slices x 16 feats, slice-major.
// Block = 32 nodes x one slice (slice = blockIdx&7). Wave = 8 nodes x 8
// lanes x 2 feats. Edge list = bare ushort src; 8 indices per uint4 load
// (after aligning j to 8). No weight math: plain adds.
// out = di*(sum h'[src] + h'[self]) + b. Outputs nt.
__global__ __launch_bounds__(256) void agg_kernel(
    const unsigned short* __restrict__ h,
    const unsigned short* __restrict__ ecol,
    const int* __restrict__ offs,
    const float* __restrict__ dinv, const float* __restrict__ bias,
    unsigned short* __restrict__ xh_out,
    unsigned short* __restrict__ xl_out,
    float* __restrict__ fout, int n) {
    int tid = threadIdx.x;
    int wave = tid >> 6, lane = tid & 63;
    int sub = lane >> 3, ln = lane & 7;
    int slice = blockIdx.x & 7;
    int node = (blockIdx.x >> 3) * 32 + wave * 8 + sub;
    if (node >= n) return;
    size_t sbase = (size_t)slice * n;  // slice-major base (16-elem rows)
    int fo = ln * 2;
    unsigned int sp = *(const unsigned int*)&h[(sbase + node) * 16 + fo];
    float ax0 = bflo(sp), ay0 = bfhi(sp);
    float ax1 = 0.f, ay1 = 0.f, ax2 = 0.f, ay2 = 0.f, ax3 = 0.f, ay3 = 0.f;
    int s = offs[node], e = offs[node + 1];
    int j = s;
    // align j to 8 (uint4 = 8 ushort indices)
    for (; j < e && (j & 7); j++) {
        unsigned int p0 = *(const unsigned int*)&h[(sbase + ecol[j]) * 16 + fo];
        ax0 += bflo(p0); ay0 += bfhi(p0);
    }
    for (; j + 8 <= e; j += 8) {
        uint4 iv = *(const uint4*)&ecol[j];
        unsigned int s0 = iv.x & 0xFFFFu, s1 = iv.x >> 16;
        unsigned int s2 = iv.y & 0xFFFFu, s3 = iv.y >> 16;
        unsigned int s4 = iv.z & 0xFFFFu, s5 = iv.z >> 16;
        unsigned int s6 = iv.w & 0xFFFFu, s7 = iv.w >> 16;
        unsigned int p0 = *(const unsigned int*)&h[(sbase + s0) * 16 + fo];
        unsigned int p1 = *(const unsigned int*)&h[(sbase + s1) * 16 + fo];
        unsigned int p2 = *(const unsigned int*)&h[(sbase + s2) * 16 + fo];
        unsigned int p3 = *(const unsigned int*)&h[(sbase + s3) * 16 + fo];
        unsigned int p4 = *(const unsigned int*)&h[(sbase + s4) * 16 + fo];
        unsigned int p5 = *(const unsigned int*)&h[(sbase + s5) * 16 + fo];
        unsigned int p6 = *(const unsigned int*)&h[(sbase + s6) * 16 + fo];
        unsigned int p7 = *(const unsigned int*)&h[(sbase + s7) * 16 + fo];
        ax0 += bflo(p0); ay0 += bfhi(p0);
        ax1 += bflo(p1); ay1 += bfhi(p1);
        ax2 += bflo(p2); ay2 += bfhi(p2);
        ax3 += bflo(p3); ay3 += bfhi(p3);
        ax0 += bflo(p4); ay0 += bfhi(p4);
        ax1 += bflo(p5); ay1 += bfhi(p5);
        ax2 += bflo(p6); ay2 += bfhi(p6);
        ax3 += bflo(p7); ay3 += bfhi(p7);
    }
    for (; j < e; j++) {
        unsigned int p0 = *(const unsigned int*)&h[(sbase + ecol[j]) * 16 + fo];
        ax0 += bflo(p0); ay0 += bfhi(p0);
    }
    float ax = (ax0 + ax1) + (ax2 + ax3);
    float ay = (ay0 + ay1) + (ay2 + ay3);
    float di = dinv[node];
    int cg = slice * 16 + fo;
    float2 b = *(const float2*)&bias[cg];
    float rx = fmaxf(fmaf(di, ax, b.x), 0.f);
    float ry = fmaxf(fmaf(di, ay, b.y), 0.f);
    if (fout) {
        unsigned long long pv = (unsigned long long)__float_as_uint(rx) |
                                ((unsigned long long)__float_as_uint(ry) << 32);
        __builtin_nontemporal_store(pv, (unsigned long long*)&fout[(size_t)node * GCN_DIM + cg]);
    } else {
        unsigned short hx = f2bf(rx), hy = f2bf(ry);
        unsigned int hp = (unsigned int)hx | ((unsigned int)hy << 16);
        unsigned short lx = f2bf(rx - bf2f(hx)), ly = f2bf(ry - bf2f(hy));
        unsigned int lp = (unsigned int)lx | ((unsigned int)ly << 16);
        __builtin_nontemporal_store(hp, (unsigned int*)&xh_out[(size_t)node * GCN_DIM + cg]);
        __builtin_nontemporal_store(lp, (unsigned int*)&xl_out[(size_t)node * GCN_DIM + cg]);
    }
}

extern "C" void kernel_launch(void* const* d_in, const int* in_sizes, int n_in,
                              void* d_out, int out_size, void* d_ws, size_t ws_size,
                              hipStream_t stream) {
    const float* x0    = (const float*)d_in[0];
    const int*   edges = (const int*)d_in[1];   // [2, E] int32: src then dst
    const float* Wall  = (const float*)d_in[2]; // [L, 128, 128]
    const float* Ball  = (const float*)d_in[3]; // [L, 128]
    float* out = (float*)d_out;

    const int n = in_sizes[0] / GCN_DIM;              // 50000
    const int E = in_sizes[1] / 2;                    // 800000
    const int L = in_sizes[2] / (GCN_DIM * GCN_DIM);  // 5

    // workspace layout
    int*   cnt    = (int*)d_ws;                        // n
    float* dinv   = (float*)(cnt + n);                 // n
    int*   offs   = (int*)(dinv + n);                  // n+16
    int*   bsum   = offs + n + 16;                     // 64
    int*   rank   = bsum + 64;                         // E
    unsigned short* ecol = (unsigned short*)(rank + E);// E (2B, 16B-aligned)
    unsigned short* h   = ecol + E;                    // n*128 bf16 (slice-major)
    unsigned short* xh  = h  + (size_t)n * GCN_DIM;    // n*128 bf16
    unsigned short* xl  = xh + (size_t)n * GCN_DIM;    // n*128 bf16
    unsigned short* Wfh = xl + (size_t)n * GCN_DIM;    // L*16384 bf16 frag-order
    unsigned short* Wfl = Wfh + (size_t)L * GCN_DIM * GCN_DIM;

    const int* src = edges;
    const int* dst = edges + E;

    int nb_n = (n + 255) / 256;
    int nb_e = (E + 255) / 256;
    int nb_scan = (n + 1023) / 1024;

    hipMemsetAsync(cnt, 0, (size_t)n * sizeof(int), stream);
    count_kernel<<<nb_e, 256, 0, stream>>>(dst, cnt, rank, E);
    scan_part_kernel<<<nb_scan, 256, 0, stream>>>(cnt, offs, bsum, n);
    scan_top_kernel<<<1, 256, 0, stream>>>(bsum, nb_scan);
    scan_add_kernel<<<nb_n, 256, 0, stream>>>(offs, bsum, cnt, dinv, n, E);
    fill_kernel<<<nb_e, 256, 0, stream>>>(src, dst, rank, offs, ecol, E);

    int xtotal = n * GCN_DIM;
    split_x_kernel<<<(xtotal / 4 + 255) / 256, 256, 0, stream>>>(x0, xh, xl, xtotal);
    int wtotal = L * GCN_DIM * GCN_DIM;
    wsplit_kernel<<<(wtotal + 255) / 256, 256, 0, stream>>>(Wall, Wfh, Wfl, wtotal);

    int gemm_blocks = (n + 63) / 64;
    int agg_blocks  = ((n + 31) / 32) * 8;  // 32 nodes x 8 slices per block

    for (int l = 0; l < L; l++) {
        gemm_mfma_kernel<<<gemm_blocks, 256, 0, stream>>>(
            xh, xl, Wfh + (size_t)l * GCN_DIM * GCN_DIM, Wfl + (size_t)l * GCN_DIM * GCN_DIM,
            dinv, h, n);
        agg_kernel<<<agg_blocks, 256, 0, stream>>>(
            h, ecol, offs, dinv, Ball + (size_t)l * GCN_DIM,
            xh, xl, (l == L - 1) ? out : nullptr, n);
    }
}